// Round 3
// baseline (679.745 us; speedup 1.0000x reference)
//
#include <hip/hip_runtime.h>
#include <hip/hip_bf16.h>
#include <cstddef>

#define B_   8
#define CIN  96
#define H_   256
#define W_   256
#define CO1  48          // conv1 output channels
#define NCH  192         // final output channels (CO1*4)
#define HO   128
#define WO   128

typedef short  v8s __attribute__((ext_vector_type(8)));   // 8 x bf16 (4 VGPRs)
typedef float  v4f __attribute__((ext_vector_type(4)));   // MFMA acc frag

static __device__ __forceinline__ unsigned short f2bf(float f) {
    __hip_bfloat16 h = __float2bfloat16(f);   // RNE
    return *(unsigned short*)&h;
}

// ---------------------------------------------------------------------------
// Prep A: w_body[co][ci][kh][kw] fp32 -> wbf[tap][co][ci] bf16
// (A-operand layout: lane = co, 8 contiguous ci per lane-quad)
// ---------------------------------------------------------------------------
__global__ void prep_weights(const float* __restrict__ wb, unsigned short* __restrict__ wbf) {
    int o = blockIdx.x * blockDim.x + threadIdx.x;      // flat over 9*48*96
    if (o >= 9 * CO1 * CIN) return;
    int ci  = o % CIN;
    int co  = (o / CIN) % CO1;
    int tap = o / (CIN * CO1);
    wbf[o] = f2bf(wb[(co * CIN + ci) * 9 + tap]);
}

// ---------------------------------------------------------------------------
// Prep B: mask (8,1,256,256) -> m_us (8,4,128,128)  (pixel-unshuffle, fp32)
// ---------------------------------------------------------------------------
__global__ void prep_mask(const float* __restrict__ mask, float* __restrict__ m_us) {
    int o = blockIdx.x * blockDim.x + threadIdx.x;      // flat over 8*4*128*128
    if (o >= B_ * 4 * HO * WO) return;
    int w1 = o & (WO - 1);
    int h1 = (o >> 7) & (HO - 1);
    int q  = (o >> 14) & 3;                             // 2*dy + dx
    int b  = o >> 16;
    int dy = q >> 1, dx = q & 1;
    m_us[o] = mask[((size_t)b * H_ + (2 * h1 + dy)) * W_ + (2 * w1 + dx)];
}

// ---------------------------------------------------------------------------
// conv1_fused: fp32 NCHW x --(bf16 cvt, LDS stage)--> MFMA implicit GEMM.
// Block = 256 thr = 4 waves; out tile = 4 rows x 64 px, all 48 co.
// LDS x-tile layout: frag16B[(r*12 + chunk)*66 + p], chunk = ks*4 + kq,
// holding ci = chunk*8 .. chunk*8+7 for pixel p, row r. Conflict-free for
// both ds_write_b128 staging and ds_read_b128 B-fragment reads.
// Output written pixel-unshuffled: y_us[b][n=4c+2dy+dx][h'][w'] fp32.
// grid = (64 h-tiles, 4 w-tiles, 8 b)
// ---------------------------------------------------------------------------
__global__ __launch_bounds__(256) void conv1_fused(const float* __restrict__ x,
                                                   const unsigned short* __restrict__ wbf,
                                                   float* __restrict__ y_us) {
    __shared__ unsigned short sx[6 * 12 * 66 * 8];      // 76032 B

    const int tid = threadIdx.x;
    const int h0  = blockIdx.x * 4;
    const int w0  = blockIdx.y * 64;
    const int b   = blockIdx.z;

    // ---- stage 6 rows x 66 px x 96 ci (fp32 -> bf16), zero-padded halo ----
    const float* xb = x + ((size_t)b * CIN << 16);
    for (int f = tid; f < 6 * 12 * 66; f += 256) {
        int p  = f % 66;
        int rc = f / 66;
        int c  = rc % 12;                               // 8-ci chunk
        int r  = rc / 12;                               // tile row
        int gh = h0 - 1 + r;
        int gw = w0 - 1 + p;
        bool ok = ((unsigned)gh < (unsigned)H_) && ((unsigned)gw < (unsigned)W_);
        const float* src = xb + ((size_t)(c * 8) << 16) + ((gh & 255) << 8) + (gw & 255);
        unsigned int d[4];
#pragma unroll
        for (int q = 0; q < 4; ++q) {
            float f0 = ok ? src[(size_t)(2 * q)     << 16] : 0.f;
            float f1 = ok ? src[(size_t)(2 * q + 1) << 16] : 0.f;
            d[q] = (unsigned int)f2bf(f0) | ((unsigned int)f2bf(f1) << 16);
        }
        ((int4*)sx)[f] = *(const int4*)d;
    }
    __syncthreads();

    // ---- MFMA phase: wave wv computes out row h0+wv, 64 px, 48 co ----
    const int lane = tid & 63;
    const int wv   = tid >> 6;
    const int l15  = lane & 15;
    const int l4   = lane >> 4;

    const unsigned short* aln = wbf + (l15 * CIN + l4 * 8);

    v4f acc[12];
#pragma unroll
    for (int i = 0; i < 12; ++i) acc[i] = (v4f){0.f, 0.f, 0.f, 0.f};

#pragma unroll
    for (int kh = 0; kh < 3; ++kh) {
#pragma unroll
        for (int kw = 0; kw < 3; ++kw) {
            const unsigned short* at = aln + (size_t)(kh * 3 + kw) * CO1 * CIN;
#pragma unroll
            for (int ks = 0; ks < 3; ++ks) {
                const unsigned short* bt = sx + ((((wv + kh) * 12 + ks * 4 + l4) * 66)
                                                 + (kw + l15)) * 8;
                v8s a0 = *(const v8s*)(at +  0 * CIN + ks * 32);
                v8s a1 = *(const v8s*)(at + 16 * CIN + ks * 32);
                v8s a2 = *(const v8s*)(at + 32 * CIN + ks * 32);
                v8s b0 = *(const v8s*)(bt + 0 * 16 * 8);
                v8s b1 = *(const v8s*)(bt + 1 * 16 * 8);
                v8s b2 = *(const v8s*)(bt + 2 * 16 * 8);
                v8s b3 = *(const v8s*)(bt + 3 * 16 * 8);
                acc[0]  = __builtin_amdgcn_mfma_f32_16x16x32_bf16(a0, b0, acc[0],  0, 0, 0);
                acc[1]  = __builtin_amdgcn_mfma_f32_16x16x32_bf16(a0, b1, acc[1],  0, 0, 0);
                acc[2]  = __builtin_amdgcn_mfma_f32_16x16x32_bf16(a0, b2, acc[2],  0, 0, 0);
                acc[3]  = __builtin_amdgcn_mfma_f32_16x16x32_bf16(a0, b3, acc[3],  0, 0, 0);
                acc[4]  = __builtin_amdgcn_mfma_f32_16x16x32_bf16(a1, b0, acc[4],  0, 0, 0);
                acc[5]  = __builtin_amdgcn_mfma_f32_16x16x32_bf16(a1, b1, acc[5],  0, 0, 0);
                acc[6]  = __builtin_amdgcn_mfma_f32_16x16x32_bf16(a1, b2, acc[6],  0, 0, 0);
                acc[7]  = __builtin_amdgcn_mfma_f32_16x16x32_bf16(a1, b3, acc[7],  0, 0, 0);
                acc[8]  = __builtin_amdgcn_mfma_f32_16x16x32_bf16(a2, b0, acc[8],  0, 0, 0);
                acc[9]  = __builtin_amdgcn_mfma_f32_16x16x32_bf16(a2, b1, acc[9],  0, 0, 0);
                acc[10] = __builtin_amdgcn_mfma_f32_16x16x32_bf16(a2, b2, acc[10], 0, 0, 0);
                acc[11] = __builtin_amdgcn_mfma_f32_16x16x32_bf16(a2, b3, acc[11], 0, 0, 0);
            }
        }
    }

    // ---- epilogue: D row = co = mf*16 + l4*4 + r ; D col = px = w0+nf*16+l15 ----
    const int h  = h0 + wv;
    const int dy = h & 1, hp1 = h >> 1;
#pragma unroll
    for (int mf = 0; mf < 3; ++mf) {
#pragma unroll
        for (int nf = 0; nf < 4; ++nf) {
            const int Wp = w0 + nf * 16 + l15;
            const int dx = Wp & 1, wp1 = Wp >> 1;
#pragma unroll
            for (int r = 0; r < 4; ++r) {
                const int co = mf * 16 + l4 * 4 + r;
                const int n  = co * 4 + dy * 2 + dx;
                y_us[(((size_t)b * NCH + n) << 14) + (hp1 << 7) + wp1] = acc[mf * 4 + nf][r];
            }
        }
    }
}

// ---------------------------------------------------------------------------
// conv2: LDS-staged unit-stride grouped 3x3 over (y_us[n], m_us[n&3]).
// block = (64,4) = 64 px x 4 rows; stage 6x66 window of both planes.
// grid = (2 w-tiles, 32 h-tiles, B_*NCH)
// ---------------------------------------------------------------------------
__global__ __launch_bounds__(256) void conv2_kernel(
    const float* __restrict__ y_us, const float* __restrict__ m_us,
    const float* __restrict__ wproj, float* __restrict__ out)
{
    __shared__ float sy[6][68];
    __shared__ float sm[6][68];

    const int tx = threadIdx.x;                        // 0..63 px
    const int ty = threadIdx.y;                        // 0..3 row
    const int tid = ty * 64 + tx;
    const int w0 = blockIdx.x * 64;
    const int h0 = blockIdx.y * 4;
    const int bn = blockIdx.z;                         // b*192 + n
    const int b  = bn / NCH;
    const int n  = bn - b * NCH;

    const float* yc = y_us + ((size_t)bn << 14);
    const float* mc = m_us + (((size_t)b * 4 + (n & 3)) << 14);

    for (int f = tid; f < 6 * 66; f += 256) {
        int r = f / 66, p = f % 66;
        int gh = h0 - 1 + r;
        int gw = w0 - 1 + p;
        bool ok = ((unsigned)gh < (unsigned)HO) && ((unsigned)gw < (unsigned)WO);
        int idx = ((gh & 127) << 7) + (gw & 127);
        sy[r][p] = ok ? yc[idx] : 0.f;
        sm[r][p] = ok ? mc[idx] : 0.f;
    }
    __syncthreads();

    const float* wp = wproj + n * 18;                  // uniform -> s_load
    float acc = 0.f;
#pragma unroll
    for (int kh = 0; kh < 3; ++kh)
#pragma unroll
        for (int kw = 0; kw < 3; ++kw) {
            acc = fmaf(wp[kh * 3 + kw],     sy[ty + kh][tx + kw], acc);
            acc = fmaf(wp[9 + kh * 3 + kw], sm[ty + kh][tx + kw], acc);
        }

    out[((size_t)bn << 14) + (h0 + ty) * WO + (w0 + tx)] = acc;
}

// ---------------------------------------------------------------------------
extern "C" void kernel_launch(void* const* d_in, const int* in_sizes, int n_in,
                              void* d_out, int out_size, void* d_ws, size_t ws_size,
                              hipStream_t stream) {
    const float* x      = (const float*)d_in[0];   // (8,96,256,256)
    const float* mask   = (const float*)d_in[1];   // (8,1,256,256)
    const float* w_body = (const float*)d_in[2];   // (48,96,3,3)
    const float* w_proj = (const float*)d_in[3];   // (192,2,3,3)
    float* out = (float*)d_out;                    // (8,192,128,128)

    // workspace layout
    char* p = (char*)d_ws;
    unsigned short* wbf  = (unsigned short*)p;  p += (9 * CO1 * CIN * 2 + 255) & ~255ull;          // 83 KB
    float*          m_us = (float*)p;           p += ((size_t)B_ * 4 * HO * WO * 4 + 255) & ~255ull; // 2 MB
    float*          y_us = (float*)p;                                                              // 100.7 MB

    {   int nel = 9 * CO1 * CIN;
        prep_weights<<<(nel + 255) / 256, 256, 0, stream>>>(w_body, wbf); }
    {   int nel = B_ * 4 * HO * WO;
        prep_mask<<<(nel + 255) / 256, 256, 0, stream>>>(mask, m_us); }
    {   dim3 grid(H_ / 4, W_ / 64, B_);
        conv1_fused<<<grid, 256, 0, stream>>>(x, wbf, y_us); }
    {   dim3 grid(WO / 64, HO / 4, B_ * NCH);
        dim3 block(64, 4, 1);
        conv2_kernel<<<grid, block, 0, stream>>>(y_us, m_us, w_proj, out); }
}